// Round 1
// baseline (814.327 us; speedup 1.0000x reference)
//
#include <hip/hip_runtime.h>
#include <hip/hip_bf16.h>
#include <math.h>

// Problem constants
#define DIMX 512
#define HEADS 8
#define DHV 64
#define CHUNKV 64
#define DHIDV 256
#define NCV 64
#define BV 2
#define NV 4096
#define BHV 16
#define OUTROW 32832   // 64 + 64*256 + 256*64

__device__ inline unsigned short f2b(float f) {
    union { float f; unsigned int u; } v; v.f = f;
    unsigned int r = v.u + 0x7FFFu + ((v.u >> 16) & 1u);  // RNE
    return (unsigned short)(r >> 16);
}
__device__ inline float b2f(unsigned short h) {
    union { unsigned int u; float f; } v; v.u = ((unsigned int)h) << 16;
    return v.f;
}

__device__ inline void gelu_both(float x, float& g, float& gp) {
    const float c0 = 0.7978845608028654f, c1 = 0.044715f;
    float x2 = x * x;
    float z  = c0 * x * (1.0f + c1 * x2);
    float t  = tanhf(z);
    g  = 0.5f * x * (1.0f + t);
    float dz = c0 * (1.0f + 3.0f * c1 * x2);
    gp = 0.5f * (1.0f + t) + 0.5f * x * (1.0f - t * t) * dz;
}

// ---------------- kernel 1: rmsnorm(seq) -> x ; chunk pooled means ----------
__global__ __launch_bounds__(256) void k_rms_pool(
    const float* __restrict__ seq, const float* __restrict__ wnorm,
    float* __restrict__ x, float* __restrict__ pooled)
{
    const int blk = blockIdx.x;          // b*64 + c
    const int tid = threadIdx.x;
    __shared__ float rb[4];
    const float w0v = wnorm[tid], w1v = wnorm[tid + 256];
    float p0 = 0.f, p1 = 0.f;
    for (int t = 0; t < 64; ++t) {
        const float* srow = seq + (size_t)(blk * 64 + t) * DIMX;
        float a = srow[tid], b = srow[tid + 256];
        float ss = a * a + b * b;
        #pragma unroll
        for (int o = 32; o > 0; o >>= 1) ss += __shfl_xor(ss, o);
        if ((tid & 63) == 0) rb[tid >> 6] = ss;
        __syncthreads();
        float tot = rb[0] + rb[1] + rb[2] + rb[3];
        float rr = rsqrtf(tot * (1.0f / 512.0f) + 1e-6f);
        float xa = a * rr * w0v, xb = b * rr * w1v;
        float* xrow = x + (size_t)(blk * 64 + t) * DIMX;
        xrow[tid] = xa; xrow[tid + 256] = xb;
        p0 += xa; p1 += xb;
        __syncthreads();
    }
    pooled[(size_t)blk * DIMX + tid]       = p0 * (1.0f / 64.0f);
    pooled[(size_t)blk * DIMX + tid + 256] = p1 * (1.0f / 64.0f);
}

// ---------------- kernel 2: x @ [Wk | Wv]  (M=8192,N=1024,K=512) ------------
__global__ __launch_bounds__(256) void k_proj(
    const float* __restrict__ x, const float* __restrict__ Wk,
    const float* __restrict__ Wv, float* __restrict__ kout, float* __restrict__ vout)
{
    const int bm = blockIdx.x >> 4;      // 0..127
    const int bn = blockIdx.x & 15;      // 0..15
    const int m0 = bm * 64, n0 = bn * 64;
    const int tid = threadIdx.x, tm = tid >> 4, tn = tid & 15;
    __shared__ float As[64][65];
    __shared__ float Bs[64][65];
    const float* W = (n0 < 512) ? (Wk + n0) : (Wv + (n0 - 512));
    float acc[4][4];
    #pragma unroll
    for (int r = 0; r < 4; ++r)
        #pragma unroll
        for (int q = 0; q < 4; ++q) acc[r][q] = 0.f;

    for (int k0 = 0; k0 < 512; k0 += 64) {
        #pragma unroll
        for (int l = 0; l < 4; ++l) {
            int gr = tid + l * 256; int r = gr >> 4, c4 = (gr & 15) * 4;
            float4 a4 = *(const float4*)(x + (size_t)(m0 + r) * DIMX + k0 + c4);
            As[r][c4 + 0] = a4.x; As[r][c4 + 1] = a4.y; As[r][c4 + 2] = a4.z; As[r][c4 + 3] = a4.w;
            float4 b4 = *(const float4*)(W + (size_t)(k0 + r) * 512 + c4);
            Bs[r][c4 + 0] = b4.x; Bs[r][c4 + 1] = b4.y; Bs[r][c4 + 2] = b4.z; Bs[r][c4 + 3] = b4.w;
        }
        __syncthreads();
        #pragma unroll 4
        for (int kk = 0; kk < 64; ++kk) {
            float av[4], bv[4];
            #pragma unroll
            for (int r = 0; r < 4; ++r) av[r] = As[tm * 4 + r][kk];
            #pragma unroll
            for (int q = 0; q < 4; ++q) bv[q] = Bs[kk][tn * 4 + q];
            #pragma unroll
            for (int r = 0; r < 4; ++r)
                #pragma unroll
                for (int q = 0; q < 4; ++q) acc[r][q] = fmaf(av[r], bv[q], acc[r][q]);
        }
        __syncthreads();
    }
    float* o = (n0 < 512) ? (kout + n0) : (vout + (n0 - 512));
    #pragma unroll
    for (int r = 0; r < 4; ++r)
        #pragma unroll
        for (int q = 0; q < 4; ++q)
            o[(size_t)(m0 + tm * 4 + r) * 512 + tn * 4 + q] = acc[r][q];
}

// ---------------- kernel 3: lr = sigmoid(x @ Wstep + bstep) -----------------
__global__ __launch_bounds__(64) void k_lr(
    const float* __restrict__ x, const float* __restrict__ Wstep,
    const float* __restrict__ bstep, float* __restrict__ lrout)
{
    const int t = blockIdx.x;
    const int tid = threadIdx.x;
    const int h = tid & 7, d0 = tid >> 3;
    const float* xr = x + (size_t)t * DIMX;
    float p = 0.f;
    #pragma unroll 8
    for (int it = 0; it < 64; ++it) {
        int d = d0 + it * 8;
        p = fmaf(xr[d], Wstep[d * 8 + h], p);
    }
    p += __shfl_xor(p, 8);
    p += __shfl_xor(p, 16);
    p += __shfl_xor(p, 32);
    if (tid < 8) lrout[(size_t)t * 8 + h] = 1.0f / (1.0f + expf(-(p + bstep[h])));
}

// ---------------- kernel 4: mom / dec gates ---------------------------------
__global__ __launch_bounds__(64) void k_gates(
    const float* __restrict__ pooled,
    const float* __restrict__ Wmom, const float* __restrict__ bmom,
    const float* __restrict__ Wdec, const float* __restrict__ bdec,
    float* __restrict__ momout, float* __restrict__ decout)
{
    const int bc = blockIdx.x;           // b*64 + c
    const int tid = threadIdx.x, h = tid & 7, d0 = tid >> 3;
    const float* pr = pooled + (size_t)bc * DIMX;
    float pm = 0.f, pd = 0.f;
    #pragma unroll 8
    for (int it = 0; it < 64; ++it) {
        int d = d0 + it * 8; float pv = pr[d];
        pm = fmaf(pv, Wmom[d * 8 + h], pm);
        pd = fmaf(pv, Wdec[d * 8 + h], pd);
    }
    #pragma unroll
    for (int o = 8; o < 64; o <<= 1) { pm += __shfl_xor(pm, o); pd += __shfl_xor(pd, o); }
    if (tid < 8) {
        momout[(size_t)bc * 8 + h] = 1.0f / (1.0f + expf(-(pm + bmom[h])));
        decout[(size_t)bc * 8 + h] = 1.0f / (1.0f + expf(-(pd + bdec[h])));
    }
}

// ---------------- kernel 5: scan coefficients per stream --------------------
// coeff[c] = P_c + M_{c+1} coeff_{c+1},  P_c = prod_{j>c}(1-d_j),  A = prod_j(1-d_j)
__global__ void k_coeff(const float* __restrict__ mom, const float* __restrict__ dec,
                        float* __restrict__ coeff, float* __restrict__ Aout)
{
    int s = threadIdx.x;
    if (s >= 16) return;
    int b = s >> 3, h = s & 7;
    float P = 1.f, S = 1.f;
    coeff[s * 64 + 63] = 1.f;
    for (int cc = 62; cc >= 0; --cc) {
        float Dn = 1.f - dec[(size_t)(b * 64 + cc + 1) * 8 + h];
        float Mn = mom[(size_t)(b * 64 + cc + 1) * 8 + h];
        P *= Dn;
        S = P + Mn * S;
        coeff[s * 64 + cc] = S;
    }
    float D0 = 1.f - dec[(size_t)(b * 64) * 8 + h];
    Aout[s] = P * D0;
}

// ---------------- kernel 6: out = A * param0 --------------------------------
__global__ __launch_bounds__(256) void k_init_out(
    const float* __restrict__ nw_g, const float* __restrict__ w0_g,
    const float* __restrict__ w1_g, const float* __restrict__ Aout,
    float* __restrict__ out)
{
    int gid = blockIdx.x * 256 + threadIdx.x;
    if (gid >= BHV * OUTROW) return;
    int s = gid / OUTROW, r = gid % OUTROW;
    int h = s & 7;
    float v;
    if (r < 64)          v = nw_g[h * 64 + r];
    else if (r < 16448)  v = w0_g[h * 16384 + (r - 64)];
    else                 v = w1_g[h * 16384 + (r - 16448)];
    out[gid] = Aout[s] * v;
}

// ---------------- kernel 7: main fwd+bwd per (stream, chunk) ----------------
__global__ __launch_bounds__(256) void k_main(
    const float* __restrict__ kbuf, const float* __restrict__ vbuf,
    const float* __restrict__ lrbuf, const float* __restrict__ coeff,
    const float* __restrict__ nw_g, const float* __restrict__ w0_g,
    const float* __restrict__ w1_g, float* __restrict__ out)
{
    const int blk = blockIdx.x;
    const int s = blk >> 6, c = blk & 63;
    const int b = s >> 3, h = s & 7;
    const int row0 = b * NV + c * 64;
    const int tid = threadIdx.x;
    const int tm = tid >> 4, tn = tid & 15;

    __shared__ float sU[64][65];            // u = normalized k
    __shared__ float sE[64][65];            // e (scaled error); later reused as nw-reduce scratch
    __shared__ float sW[64][65];            // staged weight slab
    __shared__ unsigned short sG[64][66];   // gelu(a) slab, bf16
    __shared__ unsigned short sGP[64][66];  // gelu'(a) slab, bf16
    __shared__ unsigned short sDA[64][66];  // da slab, bf16
    __shared__ float sNW[64];

    if (tid < 64) sNW[tid] = nw_g[h * 64 + tid];

    // phase 1: per-token rmsnorm of k -> sU  (wave per 16 tokens, lane = dim)
    {
        int w = tid >> 6, lane = tid & 63;
        for (int tt = 0; tt < 16; ++tt) {
            int t = w * 16 + tt;
            float kv = kbuf[(size_t)(row0 + t) * 512 + h * 64 + lane];
            float ss = kv * kv;
            #pragma unroll
            for (int o = 32; o > 0; o >>= 1) ss += __shfl_xor(ss, o);
            float rr = rsqrtf(ss * (1.0f / 64.0f) + 1e-6f);
            sU[t][lane] = kv * rr;
        }
    }
    const float coefv = coeff[s * 64 + c];
    __syncthreads();

    const float* w0h = w0_g + h * 16384;    // [64][256]
    const float* w1h = w1_g + h * 16384;    // [256][64]

    float yacc[4][4];
    #pragma unroll
    for (int r = 0; r < 4; ++r)
        #pragma unroll
        for (int q = 0; q < 4; ++q) yacc[r][q] = 0.f;

    // ---------------- forward: y = gelu((u.nw)@w0) @ w1 ----------------
    for (int is = 0; is < 4; ++is) {
        // stage sW[d][i'] = nw[d] * w0[d][is*64+i']
        #pragma unroll
        for (int l = 0; l < 4; ++l) {
            int gr = tid + l * 256; int d = gr >> 4; int i4 = (gr & 15) * 4;
            float4 wv = *(const float4*)(w0h + d * 256 + is * 64 + i4);
            float nwv = sNW[d];
            sW[d][i4 + 0] = wv.x * nwv; sW[d][i4 + 1] = wv.y * nwv;
            sW[d][i4 + 2] = wv.z * nwv; sW[d][i4 + 3] = wv.w * nwv;
        }
        __syncthreads();
        // GEMM1: a[t][i'] = sum_d u[t][d] * sW[d][i'] ; gelu -> sG, sGP
        {
            float acc[4][4];
            #pragma unroll
            for (int r = 0; r < 4; ++r)
                #pragma unroll
                for (int q = 0; q < 4; ++q) acc[r][q] = 0.f;
            #pragma unroll 4
            for (int kk = 0; kk < 64; ++kk) {
                float av[4], bv[4];
                #pragma unroll
                for (int r = 0; r < 4; ++r) av[r] = sU[tm * 4 + r][kk];
                #pragma unroll
                for (int q = 0; q < 4; ++q) bv[q] = sW[kk][tn * 4 + q];
                #pragma unroll
                for (int r = 0; r < 4; ++r)
                    #pragma unroll
                    for (int q = 0; q < 4; ++q) acc[r][q] = fmaf(av[r], bv[q], acc[r][q]);
            }
            #pragma unroll
            for (int r = 0; r < 4; ++r)
                #pragma unroll
                for (int q = 0; q < 4; ++q) {
                    float g, gp; gelu_both(acc[r][q], g, gp);
                    sG[tm * 4 + r][tn * 4 + q]  = f2b(g);
                    sGP[tm * 4 + r][tn * 4 + q] = f2b(gp);
                }
        }
        __syncthreads();
        // stage sW[i'][j] = w1[is*64+i'][j]
        #pragma unroll
        for (int l = 0; l < 4; ++l) {
            int gr = tid + l * 256; int i = gr >> 4; int j4 = (gr & 15) * 4;
            float4 wv = *(const float4*)(w1h + (is * 64 + i) * 64 + j4);
            sW[i][j4 + 0] = wv.x; sW[i][j4 + 1] = wv.y; sW[i][j4 + 2] = wv.z; sW[i][j4 + 3] = wv.w;
        }
        __syncthreads();
        // GEMM2: yacc[t][j] += g[t][i'] * w1[i'][j]
        #pragma unroll 4
        for (int kk = 0; kk < 64; ++kk) {
            float av[4], bv[4];
            #pragma unroll
            for (int r = 0; r < 4; ++r) av[r] = b2f(sG[tm * 4 + r][kk]);
            #pragma unroll
            for (int q = 0; q < 4; ++q) bv[q] = sW[kk][tn * 4 + q];
            #pragma unroll
            for (int r = 0; r < 4; ++r)
                #pragma unroll
                for (int q = 0; q < 4; ++q) yacc[r][q] = fmaf(av[r], bv[q], yacc[r][q]);
        }
        __syncthreads();
    }

    // e[t][j] = -coeff*lr_t*(2/64) * (y + k - v)
    #pragma unroll
    for (int r = 0; r < 4; ++r) {
        int t = tm * 4 + r; int grow = row0 + t;
        float lrv = lrbuf[(size_t)grow * 8 + h];
        float sc = -coefv * lrv * (2.0f / 64.0f);
        #pragma unroll
        for (int q = 0; q < 4; ++q) {
            int j = tn * 4 + q;
            float kv = kbuf[(size_t)grow * 512 + h * 64 + j];
            float vv = vbuf[(size_t)grow * 512 + h * 64 + j];
            sE[t][j] = sc * (yacc[r][q] + kv - vv);
        }
    }
    __syncthreads();

    float* outS = out + (size_t)s * OUTROW;
    float dhacc[4][4];
    #pragma unroll
    for (int r = 0; r < 4; ++r)
        #pragma unroll
        for (int q = 0; q < 4; ++q) dhacc[r][q] = 0.f;

    // ---------------- backward ----------------
    for (int is = 0; is < 4; ++is) {
        // restage nw-folded w0 slab, recompute a -> sG,sGP
        #pragma unroll
        for (int l = 0; l < 4; ++l) {
            int gr = tid + l * 256; int d = gr >> 4; int i4 = (gr & 15) * 4;
            float4 wv = *(const float4*)(w0h + d * 256 + is * 64 + i4);
            float nwv = sNW[d];
            sW[d][i4 + 0] = wv.x * nwv; sW[d][i4 + 1] = wv.y * nwv;
            sW[d][i4 + 2] = wv.z * nwv; sW[d][i4 + 3] = wv.w * nwv;
        }
        __syncthreads();
        {
            float acc[4][4];
            #pragma unroll
            for (int r = 0; r < 4; ++r)
                #pragma unroll
                for (int q = 0; q < 4; ++q) acc[r][q] = 0.f;
            #pragma unroll 4
            for (int kk = 0; kk < 64; ++kk) {
                float av[4], bv[4];
                #pragma unroll
                for (int r = 0; r < 4; ++r) av[r] = sU[tm * 4 + r][kk];
                #pragma unroll
                for (int q = 0; q < 4; ++q) bv[q] = sW[kk][tn * 4 + q];
                #pragma unroll
                for (int r = 0; r < 4; ++r)
                    #pragma unroll
                    for (int q = 0; q < 4; ++q) acc[r][q] = fmaf(av[r], bv[q], acc[r][q]);
            }
            #pragma unroll
            for (int r = 0; r < 4; ++r)
                #pragma unroll
                for (int q = 0; q < 4; ++q) {
                    float g, gp; gelu_both(acc[r][q], g, gp);
                    sG[tm * 4 + r][tn * 4 + q]  = f2b(g);
                    sGP[tm * 4 + r][tn * 4 + q] = f2b(gp);
                }
        }
        __syncthreads();
        // grad_w1[i'][j] = sum_t g[t][i'] e[t][j]  -> atomicAdd
        {
            float acc[4][4];
            #pragma unroll
            for (int r = 0; r < 4; ++r)
                #pragma unroll
                for (int q = 0; q < 4; ++q) acc[r][q] = 0.f;
            #pragma unroll 4
            for (int kk = 0; kk < 64; ++kk) {
                float av[4], bv[4];
                #pragma unroll
                for (int r = 0; r < 4; ++r) av[r] = b2f(sG[kk][tm * 4 + r]);
                #pragma unroll
                for (int q = 0; q < 4; ++q) bv[q] = sE[kk][tn * 4 + q];
                #pragma unroll
                for (int r = 0; r < 4; ++r)
                    #pragma unroll
                    for (int q = 0; q < 4; ++q) acc[r][q] = fmaf(av[r], bv[q], acc[r][q]);
            }
            #pragma unroll
            for (int r = 0; r < 4; ++r)
                #pragma unroll
                for (int q = 0; q < 4; ++q)
                    atomicAdd(outS + 16448 + (is * 64 + tm * 4 + r) * 64 + tn * 4 + q, acc[r][q]);
        }
        // stage sW[j][i'] = w1[is*64+i'][j]  (transposed) — safe: sW last read before prior sync
        #pragma unroll
        for (int l = 0; l < 4; ++l) {
            int gr = tid + l * 256; int i = gr >> 4; int j4 = (gr & 15) * 4;
            float4 wv = *(const float4*)(w1h + (is * 64 + i) * 64 + j4);
            sW[j4 + 0][i] = wv.x; sW[j4 + 1][i] = wv.y; sW[j4 + 2][i] = wv.z; sW[j4 + 3][i] = wv.w;
        }
        __syncthreads();
        // dg[t][i'] = sum_j e[t][j] w1[i'][j]; da = dg * gelu'
        {
            float acc[4][4];
            #pragma unroll
            for (int r = 0; r < 4; ++r)
                #pragma unroll
                for (int q = 0; q < 4; ++q) acc[r][q] = 0.f;
            #pragma unroll 4
            for (int kk = 0; kk < 64; ++kk) {
                float av[4], bv[4];
                #pragma unroll
                for (int r = 0; r < 4; ++r) av[r] = sE[tm * 4 + r][kk];
                #pragma unroll
                for (int q = 0; q < 4; ++q) bv[q] = sW[kk][tn * 4 + q];
                #pragma unroll
                for (int r = 0; r < 4; ++r)
                    #pragma unroll
                    for (int q = 0; q < 4; ++q) acc[r][q] = fmaf(av[r], bv[q], acc[r][q]);
            }
            #pragma unroll
            for (int r = 0; r < 4; ++r)
                #pragma unroll
                for (int q = 0; q < 4; ++q) {
                    float da = acc[r][q] * b2f(sGP[tm * 4 + r][tn * 4 + q]);
                    sDA[tm * 4 + r][tn * 4 + q] = f2b(da);
                }
        }
        __syncthreads();
        // grad_w0[d][i'] = nw[d] * sum_t u[t][d] da[t][i'] -> atomicAdd
        {
            float acc[4][4];
            #pragma unroll
            for (int r = 0; r < 4; ++r)
                #pragma unroll
                for (int q = 0; q < 4; ++q) acc[r][q] = 0.f;
            #pragma unroll 4
            for (int kk = 0; kk < 64; ++kk) {
                float av[4], bv[4];
                #pragma unroll
                for (int r = 0; r < 4; ++r) av[r] = sU[kk][tm * 4 + r];
                #pragma unroll
                for (int q = 0; q < 4; ++q) bv[q] = b2f(sDA[kk][tn * 4 + q]);
                #pragma unroll
                for (int r = 0; r < 4; ++r)
                    #pragma unroll
                    for (int q = 0; q < 4; ++q) acc[r][q] = fmaf(av[r], bv[q], acc[r][q]);
            }
            #pragma unroll
            for (int r = 0; r < 4; ++r)
                #pragma unroll
                for (int q = 0; q < 4; ++q)
                    atomicAdd(outS + 64 + (tm * 4 + r) * 256 + is * 64 + tn * 4 + q,
                              sNW[tm * 4 + r] * acc[r][q]);
        }
        // stage sW[i'][d] = w0[d][is*64+i'] (raw, transposed) — safe: last sW read pre-sync
        #pragma unroll
        for (int l = 0; l < 4; ++l) {
            int gr = tid + l * 256; int d = gr >> 4; int i4 = (gr & 15) * 4;
            float4 wv = *(const float4*)(w0h + d * 256 + is * 64 + i4);
            sW[i4 + 0][d] = wv.x; sW[i4 + 1][d] = wv.y; sW[i4 + 2][d] = wv.z; sW[i4 + 3][d] = wv.w;
        }
        __syncthreads();
        // dh[t][d] += sum_i' da[t][i'] w0[d][i']
        #pragma unroll 4
        for (int kk = 0; kk < 64; ++kk) {
            float av[4], bv[4];
            #pragma unroll
            for (int r = 0; r < 4; ++r) av[r] = b2f(sDA[tm * 4 + r][kk]);
            #pragma unroll
            for (int q = 0; q < 4; ++q) bv[q] = sW[kk][tn * 4 + q];
            #pragma unroll
            for (int r = 0; r < 4; ++r)
                #pragma unroll
                for (int q = 0; q < 4; ++q) dhacc[r][q] = fmaf(av[r], bv[q], dhacc[r][q]);
        }
        __syncthreads();
    }

    // grad_nw[d] = sum_t u[t][d] * dh[t][d]   (reduce over the 16 tm groups via sE)
    {
        float p[4] = {0.f, 0.f, 0.f, 0.f};
        #pragma unroll
        for (int r = 0; r < 4; ++r)
            #pragma unroll
            for (int q = 0; q < 4; ++q)
                p[q] = fmaf(sU[tm * 4 + r][tn * 4 + q], dhacc[r][q], p[q]);
        #pragma unroll
        for (int q = 0; q < 4; ++q) sE[tn * 4 + q][tm] = p[q];
        __syncthreads();
        if (tid < 64) {
            float sum = 0.f;
            #pragma unroll
            for (int m = 0; m < 16; ++m) sum += sE[tid][m];
            atomicAdd(outS + tid, sum);
        }
    }
}

// ---------------- launcher ---------------------------------------------------
extern "C" void kernel_launch(void* const* d_in, const int* in_sizes, int n_in,
                              void* d_out, int out_size, void* d_ws, size_t ws_size,
                              hipStream_t stream) {
    (void)in_sizes; (void)n_in; (void)out_size; (void)ws_size;
    const float* seq   = (const float*)d_in[0];
    const float* snw   = (const float*)d_in[1];
    const float* Wk    = (const float*)d_in[2];
    const float* Wv    = (const float*)d_in[3];
    const float* Wstep = (const float*)d_in[4];
    const float* bstep = (const float*)d_in[5];
    const float* Wmom  = (const float*)d_in[6];
    const float* bmom  = (const float*)d_in[7];
    const float* Wdec  = (const float*)d_in[8];
    const float* bdec  = (const float*)d_in[9];
    const float* nw_g  = (const float*)d_in[10];
    const float* w0_g  = (const float*)d_in[11];
    const float* w1_g  = (const float*)d_in[12];
    float* out = (float*)d_out;

    float* ws   = (float*)d_ws;
    float* xb   = ws;                 // 4194304
    float* kb   = xb + 4194304;       // 4194304
    float* vb   = kb + 4194304;       // 4194304
    float* lrb  = vb + 4194304;       // 65536
    float* plb  = lrb + 65536;        // 65536
    float* momb = plb + 65536;        // 1024
    float* decb = momb + 1024;        // 1024
    float* cfb  = decb + 1024;        // 1024
    float* Ab   = cfb + 1024;         // 16

    k_rms_pool<<<128, 256, 0, stream>>>(seq, snw, xb, plb);
    k_proj<<<2048, 256, 0, stream>>>(xb, Wk, Wv, kb, vb);
    k_lr<<<8192, 64, 0, stream>>>(xb, Wstep, bstep, lrb);
    k_gates<<<128, 64, 0, stream>>>(plb, Wmom, bmom, Wdec, bdec, momb, decb);
    k_coeff<<<1, 64, 0, stream>>>(momb, decb, cfb, Ab);
    k_init_out<<<2052, 256, 0, stream>>>(nw_g, w0_g, w1_g, Ab, out);
    k_main<<<1024, 256, 0, stream>>>(kb, vb, lrb, cfb, nw_g, w0_g, w1_g, out);
}

// Round 3
// 201.606 us; speedup vs baseline: 4.0392x; 4.0392x over previous
//
#include <hip/hip_runtime.h>
#include <math.h>

// ---------------- types ----------------
typedef __attribute__((ext_vector_type(8)))  __bf16 bf16x8;
typedef __attribute__((ext_vector_type(4)))  float  f32x4;
typedef __attribute__((ext_vector_type(4)))  unsigned short ushort4v;
typedef __attribute__((ext_vector_type(8)))  unsigned short ushort8v;

#define MFMA16(acc, a, b) acc = __builtin_amdgcn_mfma_f32_16x16x32_bf16((a),(b),(acc),0,0,0)

__device__ inline unsigned short f2b(float f) {
    union { float f; unsigned int u; } v; v.f = f;
    unsigned int r = v.u + 0x7FFFu + ((v.u >> 16) & 1u);  // RNE
    return (unsigned short)(r >> 16);
}
__device__ inline float b2f(unsigned short h) {
    union { unsigned int u; float f; } v; v.u = ((unsigned int)h) << 16;
    return v.f;
}
__device__ inline float tanh_fast(float z) {
    float e = __expf(2.0f * z);
    return 1.0f - 2.0f / (e + 1.0f);
}
__device__ inline float gelu_g(float x) {
    const float c0 = 0.7978845608028654f, c1 = 0.044715f;
    float z = c0 * x * (1.0f + c1 * x * x);
    return 0.5f * x * (1.0f + tanh_fast(z));
}
__device__ inline void gelu_both(float x, float& g, float& gp) {
    const float c0 = 0.7978845608028654f, c1 = 0.044715f;
    float x2 = x * x;
    float z  = c0 * x * (1.0f + c1 * x2);
    float t  = tanh_fast(z);
    g  = 0.5f * x * (1.0f + t);
    float dz = c0 * (1.0f + 3.0f * c1 * x2);
    gp = 0.5f * (1.0f + t) + 0.5f * x * (1.0f - t * t) * dz;
}
__device__ inline float sigmoidf(float x) { return 1.0f / (1.0f + __expf(-x)); }

// ---------------- weight prep: bf16 converts + transposes ----------------
__global__ __launch_bounds__(256) void k_wprep(
    const float* __restrict__ Wk, const float* __restrict__ Wv,
    const float* __restrict__ w0_g, const float* __restrict__ w1_g,
    const float* __restrict__ nw_g,
    unsigned short* __restrict__ WkvT, unsigned short* __restrict__ w0fT,
    unsigned short* __restrict__ w1T, unsigned short* __restrict__ w0N,
    unsigned short* __restrict__ w1N)
{
    const int bid = blockIdx.x, tid = threadIdx.x;
    __shared__ float tile[64][65];
    if (bid < 128) {
        int kt = bid >> 4, nt = bid & 15;
        const float* src = (nt < 8) ? Wk : Wv;
        int ncol0 = (nt & 7) * 64;
        for (int ii = 0; ii < 16; ++ii) {
            int idx = tid + ii * 256; int r = idx >> 6, cc = idx & 63;
            tile[r][cc] = src[(size_t)(kt * 64 + r) * 512 + ncol0 + cc];
        }
        __syncthreads();
        for (int ii = 0; ii < 16; ++ii) {
            int idx = tid + ii * 256; int r = idx >> 6, cc = idx & 63;
            WkvT[(size_t)(nt * 64 + r) * 512 + kt * 64 + cc] = f2b(tile[cc][r]);
        }
    } else if (bid < 160) {
        int q = bid - 128; int hh = q >> 2, it = q & 3;
        const float* w0h = w0_g + hh * 16384;
        for (int ii = 0; ii < 16; ++ii) {
            int idx = tid + ii * 256; int r = idx >> 6, cc = idx & 63;
            tile[r][cc] = w0h[r * 256 + it * 64 + cc];
        }
        __syncthreads();
        for (int ii = 0; ii < 16; ++ii) {
            int idx = tid + ii * 256; int r = idx >> 6, cc = idx & 63;
            w0fT[hh * 16384 + (it * 64 + r) * 64 + cc] = f2b(nw_g[hh * 64 + cc] * tile[cc][r]);
        }
    } else if (bid < 192) {
        int q = bid - 160; int hh = q >> 2, it = q & 3;
        const float* w1h = w1_g + hh * 16384;
        for (int ii = 0; ii < 16; ++ii) {
            int idx = tid + ii * 256; int r = idx >> 6, cc = idx & 63;
            tile[r][cc] = w1h[(it * 64 + r) * 64 + cc];
        }
        __syncthreads();
        for (int ii = 0; ii < 16; ++ii) {
            int idx = tid + ii * 256; int r = idx >> 6, cc = idx & 63;
            w1T[hh * 16384 + r * 256 + it * 64 + cc] = f2b(tile[cc][r]);
        }
    } else {
        int q = bid - 192;
        int gid = q * 2048 + tid * 8;
        const float* s; unsigned short* d;
        if (gid < 131072) { s = w0_g + gid; d = w0N + gid; }
        else              { s = w1_g + (gid - 131072); d = w1N + (gid - 131072); }
        #pragma unroll
        for (int jj = 0; jj < 8; ++jj) d[jj] = f2b(s[jj]);
    }
}

// ---------------- rmsnorm(seq)->xb(bf16)  +  lr projection (fused) --------
__global__ __launch_bounds__(256) void k_rms_lr(
    const float* __restrict__ seq, const float* __restrict__ wnorm,
    const float* __restrict__ Wstep, const float* __restrict__ bstep,
    unsigned short* __restrict__ xb, float* __restrict__ lrb)
{
    const int wid = threadIdx.x >> 6, lane = threadIdx.x & 63;
    const int t = blockIdx.x * 4 + wid;
    const float* row = seq + (size_t)t * 512 + lane * 8;
    float v[8];
    *(f32x4*)&v[0] = *(const f32x4*)row;
    *(f32x4*)&v[4] = *(const f32x4*)(row + 4);
    float ss = 0.f;
    #pragma unroll
    for (int j = 0; j < 8; ++j) ss += v[j] * v[j];
    #pragma unroll
    for (int o = 1; o < 64; o <<= 1) ss += __shfl_xor(ss, o);
    float rr = rsqrtf(ss * (1.0f / 512.0f) + 1e-6f);
    const float* wn = wnorm + lane * 8;
    ushort8v xs;
    float acc[8] = {0.f,0.f,0.f,0.f,0.f,0.f,0.f,0.f};
    #pragma unroll
    for (int j = 0; j < 8; ++j) {
        float xf = v[j] * rr * wn[j];
        xs[j] = f2b(xf);
        const float* wrow = Wstep + (size_t)(lane * 8 + j) * 8;
        #pragma unroll
        for (int h = 0; h < 8; ++h) acc[h] = fmaf(xf, wrow[h], acc[h]);
    }
    *(ushort8v*)(xb + (size_t)t * 512 + lane * 8) = xs;
    #pragma unroll
    for (int h = 0; h < 8; ++h) {
        #pragma unroll
        for (int o = 1; o < 64; o <<= 1) acc[h] += __shfl_xor(acc[h], o);
    }
    if (lane == 0) {
        #pragma unroll
        for (int h = 0; h < 8; ++h) lrb[(size_t)t * 8 + h] = sigmoidf(acc[h] + bstep[h]);
    }
}

// ---------------- chunk pooling -------------------------------------------
__global__ __launch_bounds__(256) void k_pool(
    const unsigned short* __restrict__ xb, float* __restrict__ pooled)
{
    const int bc = blockIdx.x, tid = threadIdx.x;
    float p0 = 0.f, p1 = 0.f;
    for (int t = 0; t < 64; ++t) {
        const unsigned short* r = xb + (size_t)(bc * 64 + t) * 512;
        p0 += b2f(r[tid]); p1 += b2f(r[tid + 256]);
    }
    pooled[(size_t)bc * 512 + tid]       = p0 * (1.0f / 64.0f);
    pooled[(size_t)bc * 512 + tid + 256] = p1 * (1.0f / 64.0f);
}

// ---------------- k/v projection (MFMA, 128x128 tile) ---------------------
// kb: fp32, vb: bf16
__global__ __launch_bounds__(256) void k_proj(
    const unsigned short* __restrict__ xb, const unsigned short* __restrict__ WkvT,
    float* __restrict__ kb, unsigned short* __restrict__ vb)
{
    __shared__ __attribute__((aligned(16))) unsigned short As[128][72];
    __shared__ __attribute__((aligned(16))) unsigned short Bs[128][72];
    const int tid = threadIdx.x;
    const int bm = blockIdx.x >> 3, bn = blockIdx.x & 7;
    const int m0 = bm * 128, n0 = bn * 128;
    const int wid = tid >> 6, lane = tid & 63, lg = lane >> 4, lo = lane & 15;
    const int wm = wid >> 1, wn = wid & 1;
    f32x4 acc[4][4];
    #pragma unroll
    for (int i = 0; i < 4; ++i)
        #pragma unroll
        for (int j = 0; j < 4; ++j) acc[i][j] = (f32x4)0.f;

    for (int k0 = 0; k0 < 512; k0 += 64) {
        #pragma unroll
        for (int ii = 0; ii < 4; ++ii) {
            int e0 = tid * 32 + ii * 8;
            int r = e0 >> 6, c = e0 & 63;
            *(bf16x8*)&As[r][c] = *(const bf16x8*)(xb   + (size_t)(m0 + r) * 512 + k0 + c);
            *(bf16x8*)&Bs[r][c] = *(const bf16x8*)(WkvT + (size_t)(n0 + r) * 512 + k0 + c);
        }
        __syncthreads();
        #pragma unroll
        for (int ks = 0; ks < 2; ++ks) {
            bf16x8 aF[4], bF[4];
            #pragma unroll
            for (int mt = 0; mt < 4; ++mt) aF[mt] = *(const bf16x8*)&As[wm * 64 + mt * 16 + lo][ks * 32 + 8 * lg];
            #pragma unroll
            for (int nt = 0; nt < 4; ++nt) bF[nt] = *(const bf16x8*)&Bs[wn * 64 + nt * 16 + lo][ks * 32 + 8 * lg];
            #pragma unroll
            for (int mt = 0; mt < 4; ++mt)
                #pragma unroll
                for (int nt = 0; nt < 4; ++nt) MFMA16(acc[mt][nt], aF[mt], bF[nt]);
        }
        __syncthreads();
    }
    #pragma unroll
    for (int mt = 0; mt < 4; ++mt)
        #pragma unroll
        for (int nt = 0; nt < 4; ++nt)
            #pragma unroll
            for (int r = 0; r < 4; ++r) {
                int row = m0 + wm * 64 + mt * 16 + lg * 4 + r;
                int col = n0 + wn * 64 + nt * 16 + lo;
                float val = acc[mt][nt][r];
                if (col < 512) kb[(size_t)row * 512 + col] = val;
                else           vb[(size_t)row * 512 + col - 512] = f2b(val);
            }
}

// ---------------- gates & coeff --------------------------------------------
__global__ __launch_bounds__(64) void k_gates(
    const float* __restrict__ pooled,
    const float* __restrict__ Wmom, const float* __restrict__ bmom,
    const float* __restrict__ Wdec, const float* __restrict__ bdec,
    float* __restrict__ momout, float* __restrict__ decout)
{
    const int bc = blockIdx.x;
    const int tid = threadIdx.x, h = tid & 7, d0 = tid >> 3;
    const float* pr = pooled + (size_t)bc * 512;
    float pm = 0.f, pd = 0.f;
    #pragma unroll 8
    for (int it = 0; it < 64; ++it) {
        int d = d0 + it * 8; float pv = pr[d];
        pm = fmaf(pv, Wmom[d * 8 + h], pm);
        pd = fmaf(pv, Wdec[d * 8 + h], pd);
    }
    #pragma unroll
    for (int o = 8; o < 64; o <<= 1) { pm += __shfl_xor(pm, o); pd += __shfl_xor(pd, o); }
    if (tid < 8) {
        momout[(size_t)bc * 8 + h] = sigmoidf(pm + bmom[h]);
        decout[(size_t)bc * 8 + h] = sigmoidf(pd + bdec[h]);
    }
}

__global__ void k_coeff(const float* __restrict__ mom, const float* __restrict__ dec,
                        float* __restrict__ coeff, float* __restrict__ Aout)
{
    int s = threadIdx.x;
    if (s >= 16) return;
    int b = s >> 3, h = s & 7;
    float P = 1.f, S = 1.f;
    coeff[s * 64 + 63] = 1.f;
    for (int cc = 62; cc >= 0; --cc) {
        float Dn = 1.f - dec[(size_t)(b * 64 + cc + 1) * 8 + h];
        float Mn = mom[(size_t)(b * 64 + cc + 1) * 8 + h];
        P *= Dn;
        S = P + Mn * S;
        coeff[s * 64 + cc] = S;
    }
    float D0 = 1.f - dec[(size_t)(b * 64) * 8 + h];
    Aout[s] = P * D0;
}

// ---------------- forward pass: u, y, e  (per stream-chunk) ----------------
__global__ __launch_bounds__(256) void k_fwd(
    const float* __restrict__ kb, const unsigned short* __restrict__ vb,
    const float* __restrict__ lrb, const float* __restrict__ cfb,
    const unsigned short* __restrict__ w0fT, const unsigned short* __restrict__ w1T,
    unsigned short* __restrict__ ews)
{
    __shared__ __attribute__((aligned(16))) unsigned short sU[64][72];
    __shared__ __attribute__((aligned(16))) unsigned short sG[64][72];
    const int tid = threadIdx.x, blk = blockIdx.x;
    const int s = blk >> 6, c = blk & 63;
    const int b = s >> 3, h = s & 7;
    const int row0 = b * 4096 + c * 64;
    const int wid = tid >> 6, lane = tid & 63, lg = lane >> 4, lo = lane & 15;
    const size_t ubase = (size_t)blk * 4096;

    // P0: per-token rmsnorm of k
    for (int tt = 0; tt < 16; ++tt) {
        int t = wid * 16 + tt;
        float kv = kb[(size_t)(row0 + t) * 512 + h * 64 + lane];
        float ss = kv * kv;
        #pragma unroll
        for (int o = 1; o < 64; o <<= 1) ss += __shfl_xor(ss, o);
        float rr = rsqrtf(ss * (1.0f / 64.0f) + 1e-6f);
        sU[t][lane] = f2b(kv * rr);
    }
    __syncthreads();

    const unsigned short* w0h = w0fT + h * 16384;
    const unsigned short* w1h = w1T  + h * 16384;
    bf16x8 aF0 = *(const bf16x8*)&sU[wid * 16 + lo][8 * lg];
    bf16x8 aF1 = *(const bf16x8*)&sU[wid * 16 + lo][32 + 8 * lg];

    f32x4 yac[4];
    #pragma unroll
    for (int nt = 0; nt < 4; ++nt) yac[nt] = (f32x4)0.f;

    for (int is = 0; is < 4; ++is) {
        f32x4 a1[4];
        #pragma unroll
        for (int nt = 0; nt < 4; ++nt) a1[nt] = (f32x4)0.f;
        #pragma unroll
        for (int nt = 0; nt < 4; ++nt) {
            bf16x8 b0 = *(const bf16x8*)(w0h + (size_t)(is * 64 + nt * 16 + lo) * 64 + 8 * lg);
            bf16x8 b1 = *(const bf16x8*)(w0h + (size_t)(is * 64 + nt * 16 + lo) * 64 + 32 + 8 * lg);
            MFMA16(a1[nt], aF0, b0);
            MFMA16(a1[nt], aF1, b1);
        }
        #pragma unroll
        for (int nt = 0; nt < 4; ++nt)
            #pragma unroll
            for (int r = 0; r < 4; ++r) {
                int t = wid * 16 + lg * 4 + r;
                sG[t][nt * 16 + lo] = f2b(gelu_g(a1[nt][r]));
            }
        __syncthreads();
        #pragma unroll
        for (int ks = 0; ks < 2; ++ks) {
            bf16x8 aW = *(const bf16x8*)(w1h + (size_t)(wid * 16 + lo) * 256 + is * 64 + ks * 32 + 8 * lg);
            #pragma unroll
            for (int nt = 0; nt < 4; ++nt) {
                bf16x8 bG = *(const bf16x8*)&sG[nt * 16 + lo][ks * 32 + 8 * lg];
                MFMA16(yac[nt], aW, bG);
            }
        }
        __syncthreads();
    }

    // P2: scaled error e -> ews (bf16)
    float coefv = cfb[s * 64 + c];
    #pragma unroll
    for (int nt = 0; nt < 4; ++nt) {
        int t = nt * 16 + lo; int grow = row0 + t;
        float sc = -coefv * lrb[(size_t)grow * 8 + h] * (2.0f / 64.0f);
        ushort4v ev;
        #pragma unroll
        for (int r = 0; r < 4; ++r) {
            int j = wid * 16 + lg * 4 + r;
            float kv = kb[(size_t)grow * 512 + h * 64 + j];
            float vv = b2f(vb[(size_t)grow * 512 + h * 64 + j]);
            ev[r] = f2b(sc * (yac[nt][r] + kv - vv));
        }
        *(ushort4v*)(ews + ubase + t * 64 + wid * 16 + lg * 4) = ev;
    }
}

// ---------------- backward: gradient partials (per s, kslice, islab) -------
__global__ __launch_bounds__(256) void k_bwd(
    const float* __restrict__ kb, const unsigned short* __restrict__ ews,
    const unsigned short* __restrict__ w0fT, const unsigned short* __restrict__ w0N,
    const unsigned short* __restrict__ w1N, const float* __restrict__ nw_g,
    float* __restrict__ pws)
{
    __shared__ __attribute__((aligned(16))) unsigned short sUt[64][72];
    __shared__ __attribute__((aligned(16))) unsigned short sUT[64][72];
    __shared__ __attribute__((aligned(16))) unsigned short sEt[64][72];
    __shared__ __attribute__((aligned(16))) unsigned short sGT[64][72];
    __shared__ __attribute__((aligned(16))) unsigned short sDAT[64][72];
    __shared__ __attribute__((aligned(16))) unsigned short sDAN[64][72];
    const int tid = threadIdx.x, blk = blockIdx.x;
    const int s = blk >> 4, ksl = (blk >> 2) & 3, is = blk & 3;
    const int b = s >> 3, h = s & 7;
    const int wid = tid >> 6, lane = tid & 63, lg = lane >> 4, lo = lane & 15;

    f32x4 gw1a[4], gw0a[4];
    #pragma unroll
    for (int nt = 0; nt < 4; ++nt) { gw1a[nt] = (f32x4)0.f; gw0a[nt] = (f32x4)0.f; }
    float gnwp[4] = {0.f, 0.f, 0.f, 0.f};

    const unsigned short* w0fh = w0fT + h * 16384;
    const unsigned short* w0nh = w0N  + h * 16384;
    const unsigned short* w1nh = w1N  + h * 16384;

    for (int tt = 0; tt < 16; ++tt) {
        __syncthreads();
        const int chunk = ksl * 16 + tt;
        const int row0c = b * 4096 + chunk * 64;
        size_t base = (size_t)(s * 64 + chunk) * 4096;
        // stage e
        #pragma unroll
        for (int ii = 0; ii < 2; ++ii) {
            int idx = tid * 16 + ii * 8;
            int r = idx >> 6, cc = idx & 63;
            *(bf16x8*)&sEt[r][cc] = *(const bf16x8*)(ews + base + idx);
        }
        // recompute u from kb (per-token rmsnorm), fill sUt + sUT
        for (int tt2 = 0; tt2 < 16; ++tt2) {
            int t = wid * 16 + tt2;
            float kv = kb[(size_t)(row0c + t) * 512 + h * 64 + lane];
            float ss = kv * kv;
            #pragma unroll
            for (int o = 1; o < 64; o <<= 1) ss += __shfl_xor(ss, o);
            float rr = rsqrtf(ss * (1.0f / 64.0f) + 1e-6f);
            unsigned short us = f2b(kv * rr);
            sUt[t][lane] = us;
            sUT[lane][t] = us;
        }
        __syncthreads();

        // GEMM1 recompute: a = u @ w0f
        f32x4 a1[4];
        #pragma unroll
        for (int nt = 0; nt < 4; ++nt) a1[nt] = (f32x4)0.f;
        bf16x8 aF0 = *(const bf16x8*)&sUt[wid * 16 + lo][8 * lg];
        bf16x8 aF1 = *(const bf16x8*)&sUt[wid * 16 + lo][32 + 8 * lg];
        #pragma unroll
        for (int nt = 0; nt < 4; ++nt) {
            bf16x8 b0 = *(const bf16x8*)(w0fh + (size_t)(is * 64 + nt * 16 + lo) * 64 + 8 * lg);
            bf16x8 b1 = *(const bf16x8*)(w0fh + (size_t)(is * 64 + nt * 16 + lo) * 64 + 32 + 8 * lg);
            MFMA16(a1[nt], aF0, b0);
            MFMA16(a1[nt], aF1, b1);
        }
        float gpv[4][4];
        #pragma unroll
        for (int nt = 0; nt < 4; ++nt) {
            ushort4v gv;
            #pragma unroll
            for (int r = 0; r < 4; ++r) {
                float g, gp; gelu_both(a1[nt][r], g, gp);
                gv[r] = f2b(g); gpv[nt][r] = gp;
            }
            *(ushort4v*)&sGT[nt * 16 + lo][wid * 16 + lg * 4] = gv;
        }

        // dg = e @ w1^T ; da = dg * gelu'
        f32x4 dga[4];
        #pragma unroll
        for (int nt = 0; nt < 4; ++nt) dga[nt] = (f32x4)0.f;
        bf16x8 eF0 = *(const bf16x8*)&sEt[wid * 16 + lo][8 * lg];
        bf16x8 eF1 = *(const bf16x8*)&sEt[wid * 16 + lo][32 + 8 * lg];
        #pragma unroll
        for (int nt = 0; nt < 4; ++nt) {
            bf16x8 b0 = *(const bf16x8*)(w1nh + (size_t)(is * 64 + nt * 16 + lo) * 64 + 8 * lg);
            bf16x8 b1 = *(const bf16x8*)(w1nh + (size_t)(is * 64 + nt * 16 + lo) * 64 + 32 + 8 * lg);
            MFMA16(dga[nt], eF0, b0);
            MFMA16(dga[nt], eF1, b1);
        }
        #pragma unroll
        for (int nt = 0; nt < 4; ++nt) {
            ushort4v dv;
            #pragma unroll
            for (int r = 0; r < 4; ++r) dv[r] = f2b(dga[nt][r] * gpv[nt][r]);
            *(ushort4v*)&sDAT[nt * 16 + lo][wid * 16 + lg * 4] = dv;
            #pragma unroll
            for (int r = 0; r < 4; ++r) sDAN[wid * 16 + lg * 4 + r][nt * 16 + lo] = dv[r];
        }
        __syncthreads();

        // gw1 += g^T e
        #pragma unroll
        for (int ks = 0; ks < 2; ++ks) {
            bf16x8 aG = *(const bf16x8*)&sGT[wid * 16 + lo][ks * 32 + 8 * lg];
            #pragma unroll
            for (int nt = 0; nt < 4; ++nt) {
                ushort4v lo4, hi4;
                #pragma unroll
                for (int jj = 0; jj < 4; ++jj) lo4[jj] = sEt[ks * 32 + 8 * lg + jj][nt * 16 + lo];
                #pragma unroll
                for (int jj = 0; jj < 4; ++jj) hi4[jj] = sEt[ks * 32 + 8 * lg + 4 + jj][nt * 16 + lo];
                union { ushort4v u4[2]; bf16x8 b8; } cvt;
                cvt.u4[0] = lo4; cvt.u4[1] = hi4;
                MFMA16(gw1a[nt], aG, cvt.b8);
            }
        }
        // gw0 += u^T da
        #pragma unroll
        for (int ks = 0; ks < 2; ++ks) {
            bf16x8 aU = *(const bf16x8*)&sUT[wid * 16 + lo][ks * 32 + 8 * lg];
            #pragma unroll
            for (int nt = 0; nt < 4; ++nt) {
                bf16x8 bD = *(const bf16x8*)&sDAT[nt * 16 + lo][ks * 32 + 8 * lg];
                MFMA16(gw0a[nt], aU, bD);
            }
        }
        // dhT = w0 @ da^T
        f32x4 dht[4];
        #pragma unroll
        for (int nt = 0; nt < 4; ++nt) dht[nt] = (f32x4)0.f;
        #pragma unroll
        for (int ks = 0; ks < 2; ++ks) {
            bf16x8 aW0 = *(const bf16x8*)(w0nh + (size_t)(wid * 16 + lo) * 256 + is * 64 + ks * 32 + 8 * lg);
            #pragma unroll
            for (int nt = 0; nt < 4; ++nt) {
                bf16x8 bDA = *(const bf16x8*)&sDAN[nt * 16 + lo][ks * 32 + 8 * lg];
                MFMA16(dht[nt], aW0, bDA);
            }
        }
        // gnw partial: sum_t u[t][d] * dh[d][t]
        #pragma unroll
        for (int nt = 0; nt < 4; ++nt)
            #pragma unroll
            for (int r = 0; r < 4; ++r) {
                int t = nt * 16 + lo, d = wid * 16 + lg * 4 + r;
                gnwp[r] += b2f(sUt[t][d]) * dht[nt][r];
            }
    }

    // epilogue: partials
    size_t pb = (size_t)blk * 8256;
    #pragma unroll
    for (int nt = 0; nt < 4; ++nt)
        #pragma unroll
        for (int r = 0; r < 4; ++r)
            pws[pb + (size_t)(wid * 16 + lg * 4 + r) * 64 + nt * 16 + lo] = gw1a[nt][r];
    #pragma unroll
    for (int r = 0; r < 4; ++r) {
        float nwv = nw_g[h * 64 + wid * 16 + lg * 4 + r];
        #pragma unroll
        for (int nt = 0; nt < 4; ++nt)
            pws[pb + 4096 + (size_t)(wid * 16 + lg * 4 + r) * 64 + nt * 16 + lo] = nwv * gw0a[nt][r];
    }
    #pragma unroll
    for (int r = 0; r < 4; ++r) {
        #pragma unroll
        for (int o = 1; o < 16; o <<= 1) gnwp[r] += __shfl_xor(gnwp[r], o);
    }
    if (lo == 0) {
        #pragma unroll
        for (int r = 0; r < 4; ++r)
            pws[pb + 8192 + wid * 16 + lg * 4 + r] = gnwp[r];
    }
}

// ---------------- final reduce: out = A*param0 + sum of partials -----------
__global__ __launch_bounds__(256) void k_reduce(
    const float* __restrict__ pws, const float* __restrict__ Ab,
    const float* __restrict__ nw_g, const float* __restrict__ w0_g,
    const float* __restrict__ w1_g, float* __restrict__ out)
{
    int gid = blockIdx.x * 256 + threadIdx.x;
    if (gid >= 16 * 32832) return;
    int s = gid / 32832, r = gid % 32832;
    int h = s & 7;
    float A = Ab[s];
    float val;
    if (r < 64) {
        val = A * nw_g[h * 64 + r];
        #pragma unroll
        for (int ks = 0; ks < 4; ++ks)
            #pragma unroll
            for (int i2 = 0; i2 < 4; ++i2)
                val += pws[(size_t)(s * 16 + ks * 4 + i2) * 8256 + 8192 + r];
    } else if (r < 16448) {
        int rr = r - 64; int d = rr >> 8; int i = rr & 255; int i2 = i >> 6, iloc = i & 63;
        val = A * w0_g[h * 16384 + rr];
        #pragma unroll
        for (int ks = 0; ks < 4; ++ks)
            val += pws[(size_t)(s * 16 + ks * 4 + i2) * 8256 + 4096 + d * 64 + iloc];
    } else {
        int rr = r - 16448; int i = rr >> 6; int j = rr & 63; int i2 = i >> 6, iloc = i & 63;
        val = A * w1_g[h * 16384 + rr];
        #pragma unroll
        for (int ks = 0; ks < 4; ++ks)
            val += pws[(size_t)(s * 16 + ks * 4 + i2) * 8256 + iloc * 64 + j];
    }
    out[gid] = val;
}

// ---------------- launcher -------------------------------------------------
extern "C" void kernel_launch(void* const* d_in, const int* in_sizes, int n_in,
                              void* d_out, int out_size, void* d_ws, size_t ws_size,
                              hipStream_t stream) {
    (void)in_sizes; (void)n_in; (void)out_size; (void)ws_size;
    const float* seq   = (const float*)d_in[0];
    const float* snw   = (const float*)d_in[1];
    const float* Wk    = (const float*)d_in[2];
    const float* Wv    = (const float*)d_in[3];
    const float* Wstep = (const float*)d_in[4];
    const float* bstep = (const float*)d_in[5];
    const float* Wmom  = (const float*)d_in[6];
    const float* bmom  = (const float*)d_in[7];
    const float* Wdec  = (const float*)d_in[8];
    const float* bdec  = (const float*)d_in[9];
    const float* nw_g  = (const float*)d_in[10];
    const float* w0_g  = (const float*)d_in[11];
    const float* w1_g  = (const float*)d_in[12];
    float* out = (float*)d_out;

    // workspace layout (all sizes exact; total 44,576,832 B < 50.9 MB proven-safe)
    char* ws = (char*)d_ws;
    unsigned short* xb   = (unsigned short*)(ws + 0);          //  8,388,608  (dead after k_proj)
    unsigned short* WkvT = (unsigned short*)(ws + 8388608);    //  1,048,576  (dead after k_proj)
    float*          kb   = (float*)        (ws + 9437184);     // 16,777,216  (live thru k_bwd)
    unsigned short* vb   = (unsigned short*)(ws + 26214400);   //  8,388,608  (dead after k_fwd)
    unsigned short* ews  = (unsigned short*)(ws + 34603008);   //  8,388,608
    unsigned short* w0fT = (unsigned short*)(ws + 42991616);   //    262,144
    unsigned short* w1T  = (unsigned short*)(ws + 43253760);   //    262,144
    unsigned short* w0N  = (unsigned short*)(ws + 43515904);   //    262,144
    unsigned short* w1N  = (unsigned short*)(ws + 43778048);   //    262,144
    float* lrb  = (float*)(ws + 44040192);                     //    262,144
    float* plb  = (float*)(ws + 44302336);                     //    262,144
    float* momb = (float*)(ws + 44564480);                     //      4,096
    float* decb = (float*)(ws + 44568576);                     //      4,096
    float* cfb  = (float*)(ws + 44572672);                     //      4,096
    float* Ab   = (float*)(ws + 44576768);                     //         64
    float* pws  = (float*)(ws + 0);  // 8,454,144 B — aliases xb+WkvT (dead before k_bwd)

    k_wprep <<<320, 256, 0, stream>>>(Wk, Wv, w0_g, w1_g, nw_g, WkvT, w0fT, w1T, w0N, w1N);
    k_rms_lr<<<2048, 256, 0, stream>>>(seq, snw, Wstep, bstep, xb, lrb);
    k_pool  <<<128, 256, 0, stream>>>(xb, plb);
    k_proj  <<<512, 256, 0, stream>>>(xb, WkvT, kb, vb);
    k_gates <<<128, 64, 0, stream>>>(plb, Wmom, bmom, Wdec, bdec, momb, decb);
    k_coeff <<<1, 64, 0, stream>>>(momb, decb, cfb, Ab);
    k_fwd   <<<1024, 256, 0, stream>>>(kb, vb, lrb, cfb, w0fT, w1T, ews);
    k_bwd   <<<256, 256, 0, stream>>>(kb, ews, w0fT, w0N, w1N, nw_g, pws);
    k_reduce<<<2052, 256, 0, stream>>>(pws, Ab, nw_g, w0_g, w1_g, out);
}

// Round 4
// 146.864 us; speedup vs baseline: 5.5448x; 1.3727x over previous
//
#include <hip/hip_runtime.h>
#include <math.h>

// ---------------- types ----------------
typedef __attribute__((ext_vector_type(8)))  __bf16 bf16x8;
typedef __attribute__((ext_vector_type(4)))  float  f32x4;
typedef __attribute__((ext_vector_type(4)))  unsigned short ushort4v;
typedef __attribute__((ext_vector_type(8)))  unsigned short ushort8v;

#define MFMA16(acc, a, b) acc = __builtin_amdgcn_mfma_f32_16x16x32_bf16((a),(b),(acc),0,0,0)

__device__ inline unsigned short f2b(float f) {
    union { float f; unsigned int u; } v; v.f = f;
    unsigned int r = v.u + 0x7FFFu + ((v.u >> 16) & 1u);  // RNE
    return (unsigned short)(r >> 16);
}
__device__ inline float b2f(unsigned short h) {
    union { unsigned int u; float f; } v; v.u = ((unsigned int)h) << 16;
    return v.f;
}
__device__ inline float tanh_fast(float z) {
    float e = __expf(2.0f * z);
    return 1.0f - 2.0f / (e + 1.0f);
}
__device__ inline float gelu_g(float x) {
    const float c0 = 0.7978845608028654f, c1 = 0.044715f;
    float z = c0 * x * (1.0f + c1 * x * x);
    return 0.5f * x * (1.0f + tanh_fast(z));
}
__device__ inline void gelu_both(float x, float& g, float& gp) {
    const float c0 = 0.7978845608028654f, c1 = 0.044715f;
    float x2 = x * x;
    float z  = c0 * x * (1.0f + c1 * x2);
    float t  = tanh_fast(z);
    g  = 0.5f * x * (1.0f + t);
    float dz = c0 * (1.0f + 3.0f * c1 * x2);
    gp = 0.5f * (1.0f + t) + 0.5f * x * (1.0f - t * t) * dz;
}
__device__ inline float sigmoidf(float x) { return 1.0f / (1.0f + __expf(-x)); }

// ---------------- weight prep: bf16 converts + transposes ----------------
__global__ __launch_bounds__(256) void k_wprep(
    const float* __restrict__ Wk, const float* __restrict__ Wv,
    const float* __restrict__ w0_g, const float* __restrict__ w1_g,
    const float* __restrict__ nw_g,
    unsigned short* __restrict__ WkvT, unsigned short* __restrict__ w0fT,
    unsigned short* __restrict__ w1T, unsigned short* __restrict__ w0N,
    unsigned short* __restrict__ w1N)
{
    const int bid = blockIdx.x, tid = threadIdx.x;
    __shared__ float tile[64][65];
    if (bid < 128) {
        int kt = bid >> 4, nt = bid & 15;
        const float* src = (nt < 8) ? Wk : Wv;
        int ncol0 = (nt & 7) * 64;
        for (int ii = 0; ii < 16; ++ii) {
            int idx = tid + ii * 256; int r = idx >> 6, cc = idx & 63;
            tile[r][cc] = src[(size_t)(kt * 64 + r) * 512 + ncol0 + cc];
        }
        __syncthreads();
        for (int ii = 0; ii < 16; ++ii) {
            int idx = tid + ii * 256; int r = idx >> 6, cc = idx & 63;
            WkvT[(size_t)(nt * 64 + r) * 512 + kt * 64 + cc] = f2b(tile[cc][r]);
        }
    } else if (bid < 160) {
        int q = bid - 128; int hh = q >> 2, it = q & 3;
        const float* w0h = w0_g + hh * 16384;
        for (int ii = 0; ii < 16; ++ii) {
            int idx = tid + ii * 256; int r = idx >> 6, cc = idx & 63;
            tile[r][cc] = w0h[r * 256 + it * 64 + cc];
        }
        __syncthreads();
        for (int ii = 0; ii < 16; ++ii) {
            int idx = tid + ii * 256; int r = idx >> 6, cc = idx & 63;
            w0fT[hh * 16384 + (it * 64 + r) * 64 + cc] = f2b(nw_g[hh * 64 + cc] * tile[cc][r]);
        }
    } else if (bid < 192) {
        int q = bid - 160; int hh = q >> 2, it = q & 3;
        const float* w1h = w1_g + hh * 16384;
        for (int ii = 0; ii < 16; ++ii) {
            int idx = tid + ii * 256; int r = idx >> 6, cc = idx & 63;
            tile[r][cc] = w1h[(it * 64 + r) * 64 + cc];
        }
        __syncthreads();
        for (int ii = 0; ii < 16; ++ii) {
            int idx = tid + ii * 256; int r = idx >> 6, cc = idx & 63;
            w1T[hh * 16384 + r * 256 + it * 64 + cc] = f2b(tile[cc][r]);
        }
    } else {
        int q = bid - 192;
        int gid = q * 2048 + tid * 8;
        const float* s; unsigned short* d;
        if (gid < 131072) { s = w0_g + gid; d = w0N + gid; }
        else              { s = w1_g + (gid - 131072); d = w1N + (gid - 131072); }
        #pragma unroll
        for (int jj = 0; jj < 8; ++jj) d[jj] = f2b(s[jj]);
    }
}

// ---------------- rmsnorm(seq)->xb(bf16)  +  lr projection (fused) --------
__global__ __launch_bounds__(256) void k_rms_lr(
    const float* __restrict__ seq, const float* __restrict__ wnorm,
    const float* __restrict__ Wstep, const float* __restrict__ bstep,
    unsigned short* __restrict__ xb, float* __restrict__ lrb)
{
    const int wid = threadIdx.x >> 6, lane = threadIdx.x & 63;
    const int t = blockIdx.x * 4 + wid;
    const float* row = seq + (size_t)t * 512 + lane * 8;
    float v[8];
    *(f32x4*)&v[0] = *(const f32x4*)row;
    *(f32x4*)&v[4] = *(const f32x4*)(row + 4);
    float ss = 0.f;
    #pragma unroll
    for (int j = 0; j < 8; ++j) ss += v[j] * v[j];
    #pragma unroll
    for (int o = 1; o < 64; o <<= 1) ss += __shfl_xor(ss, o);
    float rr = rsqrtf(ss * (1.0f / 512.0f) + 1e-6f);
    const float* wn = wnorm + lane * 8;
    ushort8v xs;
    float acc[8] = {0.f,0.f,0.f,0.f,0.f,0.f,0.f,0.f};
    #pragma unroll
    for (int j = 0; j < 8; ++j) {
        float xf = v[j] * rr * wn[j];
        xs[j] = f2b(xf);
        const float* wrow = Wstep + (size_t)(lane * 8 + j) * 8;
        #pragma unroll
        for (int h = 0; h < 8; ++h) acc[h] = fmaf(xf, wrow[h], acc[h]);
    }
    *(ushort8v*)(xb + (size_t)t * 512 + lane * 8) = xs;
    #pragma unroll
    for (int h = 0; h < 8; ++h) {
        #pragma unroll
        for (int o = 1; o < 64; o <<= 1) acc[h] += __shfl_xor(acc[h], o);
    }
    if (lane == 0) {
        #pragma unroll
        for (int h = 0; h < 8; ++h) lrb[(size_t)t * 8 + h] = sigmoidf(acc[h] + bstep[h]);
    }
}

// ---------------- chunk pooling -------------------------------------------
__global__ __launch_bounds__(256) void k_pool(
    const unsigned short* __restrict__ xb, float* __restrict__ pooled)
{
    const int bc = blockIdx.x, tid = threadIdx.x;
    float p0 = 0.f, p1 = 0.f;
    for (int t = 0; t < 64; ++t) {
        const unsigned short* r = xb + (size_t)(bc * 64 + t) * 512;
        p0 += b2f(r[tid]); p1 += b2f(r[tid + 256]);
    }
    pooled[(size_t)bc * 512 + tid]       = p0 * (1.0f / 64.0f);
    pooled[(size_t)bc * 512 + tid + 256] = p1 * (1.0f / 64.0f);
}

// ---------------- k/v projection (MFMA, 128x128 tile) ---------------------
// kb: fp32, vb: bf16
__global__ __launch_bounds__(256) void k_proj(
    const unsigned short* __restrict__ xb, const unsigned short* __restrict__ WkvT,
    float* __restrict__ kb, unsigned short* __restrict__ vb)
{
    __shared__ __attribute__((aligned(16))) unsigned short As[128][72];
    __shared__ __attribute__((aligned(16))) unsigned short Bs[128][72];
    const int tid = threadIdx.x;
    const int bm = blockIdx.x >> 3, bn = blockIdx.x & 7;
    const int m0 = bm * 128, n0 = bn * 128;
    const int wid = tid >> 6, lane = tid & 63, lg = lane >> 4, lo = lane & 15;
    const int wm = wid >> 1, wn = wid & 1;
    f32x4 acc[4][4];
    #pragma unroll
    for (int i = 0; i < 4; ++i)
        #pragma unroll
        for (int j = 0; j < 4; ++j) acc[i][j] = (f32x4)0.f;

    for (int k0 = 0; k0 < 512; k0 += 64) {
        #pragma unroll
        for (int ii = 0; ii < 4; ++ii) {
            int e0 = tid * 32 + ii * 8;
            int r = e0 >> 6, c = e0 & 63;
            *(bf16x8*)&As[r][c] = *(const bf16x8*)(xb   + (size_t)(m0 + r) * 512 + k0 + c);
            *(bf16x8*)&Bs[r][c] = *(const bf16x8*)(WkvT + (size_t)(n0 + r) * 512 + k0 + c);
        }
        __syncthreads();
        #pragma unroll
        for (int ks = 0; ks < 2; ++ks) {
            bf16x8 aF[4], bF[4];
            #pragma unroll
            for (int mt = 0; mt < 4; ++mt) aF[mt] = *(const bf16x8*)&As[wm * 64 + mt * 16 + lo][ks * 32 + 8 * lg];
            #pragma unroll
            for (int nt = 0; nt < 4; ++nt) bF[nt] = *(const bf16x8*)&Bs[wn * 64 + nt * 16 + lo][ks * 32 + 8 * lg];
            #pragma unroll
            for (int mt = 0; mt < 4; ++mt)
                #pragma unroll
                for (int nt = 0; nt < 4; ++nt) MFMA16(acc[mt][nt], aF[mt], bF[nt]);
        }
        __syncthreads();
    }
    #pragma unroll
    for (int mt = 0; mt < 4; ++mt)
        #pragma unroll
        for (int nt = 0; nt < 4; ++nt)
            #pragma unroll
            for (int r = 0; r < 4; ++r) {
                int row = m0 + wm * 64 + mt * 16 + lg * 4 + r;
                int col = n0 + wn * 64 + nt * 16 + lo;
                float val = acc[mt][nt][r];
                if (col < 512) kb[(size_t)row * 512 + col] = val;
                else           vb[(size_t)row * 512 + col - 512] = f2b(val);
            }
}

// ---------------- gates & coeff --------------------------------------------
__global__ __launch_bounds__(64) void k_gates(
    const float* __restrict__ pooled,
    const float* __restrict__ Wmom, const float* __restrict__ bmom,
    const float* __restrict__ Wdec, const float* __restrict__ bdec,
    float* __restrict__ momout, float* __restrict__ decout)
{
    const int bc = blockIdx.x;
    const int tid = threadIdx.x, h = tid & 7, d0 = tid >> 3;
    const float* pr = pooled + (size_t)bc * 512;
    float pm = 0.f, pd = 0.f;
    #pragma unroll 8
    for (int it = 0; it < 64; ++it) {
        int d = d0 + it * 8; float pv = pr[d];
        pm = fmaf(pv, Wmom[d * 8 + h], pm);
        pd = fmaf(pv, Wdec[d * 8 + h], pd);
    }
    #pragma unroll
    for (int o = 8; o < 64; o <<= 1) { pm += __shfl_xor(pm, o); pd += __shfl_xor(pd, o); }
    if (tid < 8) {
        momout[(size_t)bc * 8 + h] = sigmoidf(pm + bmom[h]);
        decout[(size_t)bc * 8 + h] = sigmoidf(pd + bdec[h]);
    }
}

__global__ void k_coeff(const float* __restrict__ mom, const float* __restrict__ dec,
                        float* __restrict__ coeff, float* __restrict__ Aout)
{
    int s = threadIdx.x;
    if (s >= 16) return;
    int b = s >> 3, h = s & 7;
    float P = 1.f, S = 1.f;
    coeff[s * 64 + 63] = 1.f;
    for (int cc = 62; cc >= 0; --cc) {
        float Dn = 1.f - dec[(size_t)(b * 64 + cc + 1) * 8 + h];
        float Mn = mom[(size_t)(b * 64 + cc + 1) * 8 + h];
        P *= Dn;
        S = P + Mn * S;
        coeff[s * 64 + cc] = S;
    }
    float D0 = 1.f - dec[(size_t)(b * 64) * 8 + h];
    Aout[s] = P * D0;
}

// ---------------- forward pass: u, y, e  (per stream-chunk) ----------------
// writes uws (bf16 normalized k) and ews (bf16 scaled error)
__global__ __launch_bounds__(256) void k_fwd(
    const float* __restrict__ kb, const unsigned short* __restrict__ vb,
    const float* __restrict__ lrb, const float* __restrict__ cfb,
    const unsigned short* __restrict__ w0fT, const unsigned short* __restrict__ w1T,
    unsigned short* __restrict__ uws, unsigned short* __restrict__ ews)
{
    __shared__ __attribute__((aligned(16))) unsigned short sU[64][72];
    __shared__ __attribute__((aligned(16))) unsigned short sG[64][72];
    const int tid = threadIdx.x, blk = blockIdx.x;
    const int s = blk >> 6, c = blk & 63;
    const int b = s >> 3, h = s & 7;
    const int row0 = b * 4096 + c * 64;
    const int wid = tid >> 6, lane = tid & 63, lg = lane >> 4, lo = lane & 15;
    const size_t ubase = (size_t)blk * 4096;

    // P0: per-token rmsnorm of k
    for (int tt = 0; tt < 16; ++tt) {
        int t = wid * 16 + tt;
        float kv = kb[(size_t)(row0 + t) * 512 + h * 64 + lane];
        float ss = kv * kv;
        #pragma unroll
        for (int o = 1; o < 64; o <<= 1) ss += __shfl_xor(ss, o);
        float rr = rsqrtf(ss * (1.0f / 64.0f) + 1e-6f);
        sU[t][lane] = f2b(kv * rr);
    }
    __syncthreads();
    // write u to global (vectorized from LDS)
    {
        int r = tid >> 2, c0 = (tid & 3) * 16;
        *(ushort8v*)(uws + ubase + r * 64 + c0)     = *(const ushort8v*)&sU[r][c0];
        *(ushort8v*)(uws + ubase + r * 64 + c0 + 8) = *(const ushort8v*)&sU[r][c0 + 8];
    }

    const unsigned short* w0h = w0fT + h * 16384;
    const unsigned short* w1h = w1T  + h * 16384;
    bf16x8 aF0 = *(const bf16x8*)&sU[wid * 16 + lo][8 * lg];
    bf16x8 aF1 = *(const bf16x8*)&sU[wid * 16 + lo][32 + 8 * lg];

    f32x4 yac[4];
    #pragma unroll
    for (int nt = 0; nt < 4; ++nt) yac[nt] = (f32x4)0.f;

    for (int is = 0; is < 4; ++is) {
        f32x4 a1[4];
        #pragma unroll
        for (int nt = 0; nt < 4; ++nt) a1[nt] = (f32x4)0.f;
        #pragma unroll
        for (int nt = 0; nt < 4; ++nt) {
            bf16x8 b0 = *(const bf16x8*)(w0h + (size_t)(is * 64 + nt * 16 + lo) * 64 + 8 * lg);
            bf16x8 b1 = *(const bf16x8*)(w0h + (size_t)(is * 64 + nt * 16 + lo) * 64 + 32 + 8 * lg);
            MFMA16(a1[nt], aF0, b0);
            MFMA16(a1[nt], aF1, b1);
        }
        if (is > 0) __syncthreads();   // protect sG reuse
        #pragma unroll
        for (int nt = 0; nt < 4; ++nt)
            #pragma unroll
            for (int r = 0; r < 4; ++r) {
                int t = wid * 16 + lg * 4 + r;
                sG[t][nt * 16 + lo] = f2b(gelu_g(a1[nt][r]));
            }
        __syncthreads();
        #pragma unroll
        for (int ks = 0; ks < 2; ++ks) {
            bf16x8 aW = *(const bf16x8*)(w1h + (size_t)(wid * 16 + lo) * 256 + is * 64 + ks * 32 + 8 * lg);
            #pragma unroll
            for (int nt = 0; nt < 4; ++nt) {
                bf16x8 bG = *(const bf16x8*)&sG[nt * 16 + lo][ks * 32 + 8 * lg];
                MFMA16(yac[nt], aW, bG);
            }
        }
    }

    // P2: scaled error e -> ews (bf16)
    float coefv = cfb[s * 64 + c];
    #pragma unroll
    for (int nt = 0; nt < 4; ++nt) {
        int t = nt * 16 + lo; int grow = row0 + t;
        float sc = -coefv * lrb[(size_t)grow * 8 + h] * (2.0f / 64.0f);
        ushort4v ev;
        #pragma unroll
        for (int r = 0; r < 4; ++r) {
            int j = wid * 16 + lg * 4 + r;
            float kv = kb[(size_t)grow * 512 + h * 64 + j];
            float vv = b2f(vb[(size_t)grow * 512 + h * 64 + j]);
            ev[r] = f2b(sc * (yac[nt][r] + kv - vv));
        }
        *(ushort4v*)(ews + ubase + t * 64 + wid * 16 + lg * 4) = ev;
    }
}

// ---------------- backward: gradient partials (per s, kslice/8, islab) -----
__global__ __launch_bounds__(256) void k_bwd(
    const unsigned short* __restrict__ uws, const unsigned short* __restrict__ ews,
    const unsigned short* __restrict__ w0fT, const unsigned short* __restrict__ w0N,
    const unsigned short* __restrict__ w1N, const float* __restrict__ nw_g,
    float* __restrict__ pws)
{
    __shared__ __attribute__((aligned(16))) unsigned short sUt[64][72];
    __shared__ __attribute__((aligned(16))) unsigned short sUT[64][72];
    __shared__ __attribute__((aligned(16))) unsigned short sET[64][72];
    __shared__ __attribute__((aligned(16))) unsigned short sGT[64][72];
    __shared__ __attribute__((aligned(16))) unsigned short sDAT[64][72];
    __shared__ __attribute__((aligned(16))) unsigned short sDAN[64][72];
    const int tid = threadIdx.x, blk = blockIdx.x;
    const int s = blk >> 5, ksl = (blk >> 2) & 7, is = blk & 3;
    const int h = s & 7;
    const int wid = tid >> 6, lane = tid & 63, lg = lane >> 4, lo = lane & 15;

    f32x4 gw1a[4], gw0a[4];
    #pragma unroll
    for (int nt = 0; nt < 4; ++nt) { gw1a[nt] = (f32x4)0.f; gw0a[nt] = (f32x4)0.f; }
    float gnwp[4] = {0.f, 0.f, 0.f, 0.f};

    const unsigned short* w0fh = w0fT + h * 16384;
    const unsigned short* w0nh = w0N  + h * 16384;
    const unsigned short* w1nh = w1N  + h * 16384;
    const int srow = tid >> 2, sc0 = (tid & 3) * 16;   // staging coords

    for (int tt = 0; tt < 8; ++tt) {
        __syncthreads();
        const int chunk = ksl * 8 + tt;
        const size_t base = (size_t)(s * 64 + chunk) * 4096;
        // stage u (rows + transpose) and eT
        {
            ushort8v u0 = *(const ushort8v*)(uws + base + srow * 64 + sc0);
            ushort8v u1 = *(const ushort8v*)(uws + base + srow * 64 + sc0 + 8);
            *(ushort8v*)&sUt[srow][sc0]     = u0;
            *(ushort8v*)&sUt[srow][sc0 + 8] = u1;
            #pragma unroll
            for (int jj = 0; jj < 8; ++jj) { sUT[sc0 + jj][srow] = u0[jj]; sUT[sc0 + 8 + jj][srow] = u1[jj]; }
            ushort8v e0 = *(const ushort8v*)(ews + base + srow * 64 + sc0);
            ushort8v e1 = *(const ushort8v*)(ews + base + srow * 64 + sc0 + 8);
            #pragma unroll
            for (int jj = 0; jj < 8; ++jj) { sET[sc0 + jj][srow] = e0[jj]; sET[sc0 + 8 + jj][srow] = e1[jj]; }
        }
        __syncthreads();

        // GEMM1 recompute: a = u @ w0f
        f32x4 a1[4];
        #pragma unroll
        for (int nt = 0; nt < 4; ++nt) a1[nt] = (f32x4)0.f;
        bf16x8 aF0 = *(const bf16x8*)&sUt[wid * 16 + lo][8 * lg];
        bf16x8 aF1 = *(const bf16x8*)&sUt[wid * 16 + lo][32 + 8 * lg];
        #pragma unroll
        for (int nt = 0; nt < 4; ++nt) {
            bf16x8 b0 = *(const bf16x8*)(w0fh + (size_t)(is * 64 + nt * 16 + lo) * 64 + 8 * lg);
            bf16x8 b1 = *(const bf16x8*)(w0fh + (size_t)(is * 64 + nt * 16 + lo) * 64 + 32 + 8 * lg);
            MFMA16(a1[nt], aF0, b0);
            MFMA16(a1[nt], aF1, b1);
        }
        float gpv[4][4];
        #pragma unroll
        for (int nt = 0; nt < 4; ++nt) {
            ushort4v gv;
            #pragma unroll
            for (int r = 0; r < 4; ++r) {
                float g, gp; gelu_both(a1[nt][r], g, gp);
                gv[r] = f2b(g); gpv[nt][r] = gp;
            }
            *(ushort4v*)&sGT[nt * 16 + lo][wid * 16 + lg * 4] = gv;
        }

        // dg = e @ w1^T ; da = dg * gelu'   (e rows direct from global, L2-hit)
        f32x4 dga[4];
        #pragma unroll
        for (int nt = 0; nt < 4; ++nt) dga[nt] = (f32x4)0.f;
        bf16x8 eF0 = *(const bf16x8*)(ews + base + (size_t)(wid * 16 + lo) * 64 + 8 * lg);
        bf16x8 eF1 = *(const bf16x8*)(ews + base + (size_t)(wid * 16 + lo) * 64 + 32 + 8 * lg);
        #pragma unroll
        for (int nt = 0; nt < 4; ++nt) {
            bf16x8 b0 = *(const bf16x8*)(w1nh + (size_t)(is * 64 + nt * 16 + lo) * 64 + 8 * lg);
            bf16x8 b1 = *(const bf16x8*)(w1nh + (size_t)(is * 64 + nt * 16 + lo) * 64 + 32 + 8 * lg);
            MFMA16(dga[nt], eF0, b0);
            MFMA16(dga[nt], eF1, b1);
        }
        #pragma unroll
        for (int nt = 0; nt < 4; ++nt) {
            ushort4v dv;
            #pragma unroll
            for (int r = 0; r < 4; ++r) dv[r] = f2b(dga[nt][r] * gpv[nt][r]);
            *(ushort4v*)&sDAT[nt * 16 + lo][wid * 16 + lg * 4] = dv;
            #pragma unroll
            for (int r = 0; r < 4; ++r) sDAN[wid * 16 + lg * 4 + r][nt * 16 + lo] = dv[r];
        }
        __syncthreads();

        // gw1 += g^T e   (A: sGT rows; B: sET rows)
        #pragma unroll
        for (int ks = 0; ks < 2; ++ks) {
            bf16x8 aG = *(const bf16x8*)&sGT[wid * 16 + lo][ks * 32 + 8 * lg];
            #pragma unroll
            for (int nt = 0; nt < 4; ++nt) {
                bf16x8 bE = *(const bf16x8*)&sET[nt * 16 + lo][ks * 32 + 8 * lg];
                MFMA16(gw1a[nt], aG, bE);
            }
        }
        // gw0 += u^T da  (A: sUT rows; B: sDAT rows)
        #pragma unroll
        for (int ks = 0; ks < 2; ++ks) {
            bf16x8 aU = *(const bf16x8*)&sUT[wid * 16 + lo][ks * 32 + 8 * lg];
            #pragma unroll
            for (int nt = 0; nt < 4; ++nt) {
                bf16x8 bD = *(const bf16x8*)&sDAT[nt * 16 + lo][ks * 32 + 8 * lg];
                MFMA16(gw0a[nt], aU, bD);
            }
        }
        // dhT = w0 @ da^T  (A: w0N global rows; B: sDAN rows)
        f32x4 dht[4];
        #pragma unroll
        for (int nt = 0; nt < 4; ++nt) dht[nt] = (f32x4)0.f;
        #pragma unroll
        for (int ks = 0; ks < 2; ++ks) {
            bf16x8 aW0 = *(const bf16x8*)(w0nh + (size_t)(wid * 16 + lo) * 256 + is * 64 + ks * 32 + 8 * lg);
            #pragma unroll
            for (int nt = 0; nt < 4; ++nt) {
                bf16x8 bDA = *(const bf16x8*)&sDAN[nt * 16 + lo][ks * 32 + 8 * lg];
                MFMA16(dht[nt], aW0, bDA);
            }
        }
        // gnw partial: sum_t u[t][d] * dh[d][t]
        #pragma unroll
        for (int nt = 0; nt < 4; ++nt)
            #pragma unroll
            for (int r = 0; r < 4; ++r) {
                int t = nt * 16 + lo, d = wid * 16 + lg * 4 + r;
                gnwp[r] += b2f(sUt[t][d]) * dht[nt][r];
            }
    }

    // epilogue: partials
    size_t pb = (size_t)blk * 8256;
    #pragma unroll
    for (int nt = 0; nt < 4; ++nt)
        #pragma unroll
        for (int r = 0; r < 4; ++r)
            pws[pb + (size_t)(wid * 16 + lg * 4 + r) * 64 + nt * 16 + lo] = gw1a[nt][r];
    #pragma unroll
    for (int r = 0; r < 4; ++r) {
        float nwv = nw_g[h * 64 + wid * 16 + lg * 4 + r];
        #pragma unroll
        for (int nt = 0; nt < 4; ++nt)
            pws[pb + 4096 + (size_t)(wid * 16 + lg * 4 + r) * 64 + nt * 16 + lo] = nwv * gw0a[nt][r];
    }
    #pragma unroll
    for (int r = 0; r < 4; ++r) {
        #pragma unroll
        for (int o = 1; o < 16; o <<= 1) gnwp[r] += __shfl_xor(gnwp[r], o);
    }
    if (lo == 0) {
        #pragma unroll
        for (int r = 0; r < 4; ++r)
            pws[pb + 8192 + wid * 16 + lg * 4 + r] = gnwp[r];
    }
}

// ---------------- final reduce: out = A*param0 + sum of partials -----------
__global__ __launch_bounds__(256) void k_reduce(
    const float* __restrict__ pws, const float* __restrict__ Ab,
    const float* __restrict__ nw_g, const float* __restrict__ w0_g,
    const float* __restrict__ w1_g, float* __restrict__ out)
{
    int gid = blockIdx.x * 256 + threadIdx.x;
    if (gid >= 16 * 32832) return;
    int s = gid / 32832, r = gid % 32832;
    int h = s & 7;
    float A = Ab[s];
    float val;
    if (r < 64) {
        val = A * nw_g[h * 64 + r];
        #pragma unroll
        for (int ks = 0; ks < 8; ++ks)
            #pragma unroll
            for (int i2 = 0; i2 < 4; ++i2)
                val += pws[(size_t)(s * 32 + ks * 4 + i2) * 8256 + 8192 + r];
    } else if (r < 16448) {
        int rr = r - 64; int d = rr >> 8; int i = rr & 255; int i2 = i >> 6, iloc = i & 63;
        val = A * w0_g[h * 16384 + rr];
        #pragma unroll
        for (int ks = 0; ks < 8; ++ks)
            val += pws[(size_t)(s * 32 + ks * 4 + i2) * 8256 + 4096 + d * 64 + iloc];
    } else {
        int rr = r - 16448; int i = rr >> 6; int j = rr & 63; int i2 = i >> 6, iloc = i & 63;
        val = A * w1_g[h * 16384 + rr];
        #pragma unroll
        for (int ks = 0; ks < 8; ++ks)
            val += pws[(size_t)(s * 32 + ks * 4 + i2) * 8256 + iloc * 64 + j];
    }
    out[gid] = val;
}

// ---------------- launcher -------------------------------------------------
extern "C" void kernel_launch(void* const* d_in, const int* in_sizes, int n_in,
                              void* d_out, int out_size, void* d_ws, size_t ws_size,
                              hipStream_t stream) {
    (void)in_sizes; (void)n_in; (void)out_size; (void)ws_size;
    const float* seq   = (const float*)d_in[0];
    const float* snw   = (const float*)d_in[1];
    const float* Wk    = (const float*)d_in[2];
    const float* Wv    = (const float*)d_in[3];
    const float* Wstep = (const float*)d_in[4];
    const float* bstep = (const float*)d_in[5];
    const float* Wmom  = (const float*)d_in[6];
    const float* bmom  = (const float*)d_in[7];
    const float* Wdec  = (const float*)d_in[8];
    const float* bdec  = (const float*)d_in[9];
    const float* nw_g  = (const float*)d_in[10];
    const float* w0_g  = (const float*)d_in[11];
    const float* w1_g  = (const float*)d_in[12];
    float* out = (float*)d_out;

    // workspace layout (max offset 44,576,832 B — same budget as R3)
    char* ws = (char*)d_ws;
    unsigned short* xb   = (unsigned short*)(ws + 0);          //  8,388,608  (dead after k_proj)
    unsigned short* WkvT = (unsigned short*)(ws + 8388608);    //  1,048,576  (dead after k_proj)
    float*          kb   = (float*)        (ws + 9437184);     // 16,777,216  (dead after k_fwd)
    unsigned short* vb   = (unsigned short*)(ws + 26214400);   //  8,388,608  (dead after k_fwd)
    unsigned short* ews  = (unsigned short*)(ws + 34603008);   //  8,388,608
    unsigned short* w0fT = (unsigned short*)(ws + 42991616);   //    262,144
    unsigned short* w1T  = (unsigned short*)(ws + 43253760);   //    262,144
    unsigned short* w0N  = (unsigned short*)(ws + 43515904);   //    262,144
    unsigned short* w1N  = (unsigned short*)(ws + 43778048);   //    262,144
    float* lrb  = (float*)(ws + 44040192);                     //    262,144
    float* plb  = (float*)(ws + 44302336);                     //    262,144
    float* momb = (float*)(ws + 44564480);                     //      4,096
    float* decb = (float*)(ws + 44568576);                     //      4,096
    float* cfb  = (float*)(ws + 44572672);                     //      4,096
    float* Ab   = (float*)(ws + 44576768);                     //         64
    unsigned short* uws = (unsigned short*)(ws + 0);           //  8,388,608 — aliases xb (dead before k_fwd)
    float* pws  = (float*)(ws + 9437184);  // 16,908,288 B — aliases kb + head of vb (dead before k_bwd)

    k_wprep <<<320, 256, 0, stream>>>(Wk, Wv, w0_g, w1_g, nw_g, WkvT, w0fT, w1T, w0N, w1N);
    k_rms_lr<<<2048, 256, 0, stream>>>(seq, snw, Wstep, bstep, xb, lrb);
    k_pool  <<<128, 256, 0, stream>>>(xb, plb);
    k_proj  <<<512, 256, 0, stream>>>(xb, WkvT, kb, vb);
    k_gates <<<128, 64, 0, stream>>>(plb, Wmom, bmom, Wdec, bdec, momb, decb);
    k_coeff <<<1, 64, 0, stream>>>(momb, decb, cfb, Ab);
    k_fwd   <<<1024, 256, 0, stream>>>(kb, vb, lrb, cfb, w0fT, w1T, uws, ews);
    k_bwd   <<<512, 256, 0, stream>>>(uws, ews, w0fT, w0N, w1N, nw_g, pws);
    k_reduce<<<2052, 256, 0, stream>>>(pws, Ab, nw_g, w0_g, w1_g, out);
}